// Round 4
// baseline (154.970 us; speedup 1.0000x reference)
//
#include <hip/hip_runtime.h>
#include <math.h>

// Problem constants: B=16, T=8192, N=32, depth=31, 5 ops. n = 131072 elements.
constexpr int N_STACK = 32;
constexpr int DEPTH   = 31;
constexpr int NOPS    = 5;
constexpr int BLOCK   = 64;               // ONE WAVE per block: no barriers needed
constexpr int CH      = 7;                // steps per staged ops chunk
constexpr int CH_DW   = CH * NOPS;        // 35 dwords per elem per chunk
constexpr int LAST_ST = DEPTH - 4 * CH;   // 3 steps in last chunk
constexpr int LAST_DW = LAST_ST * NOPS;   // 15
constexpr int ROW     = DEPTH * NOPS;     // 155 dwords per elem in ops
constexpr int SPAD    = 33;               // padded stack row (33 coprime-ish w/ 32 banks)
constexpr int LDS_DW  = 2 * 64 * SPAD;    // 4224 dwords = 16.9 KB (ops buf overlays it)

#define LOG_LIMF 10.0f
#define SB() __builtin_amdgcn_sched_barrier(0)   // pin load-issue points

// _clip_log(l) = tanh(l/10)*10, via tanh(x) = (e^{2x}-1)/(e^{2x}+1)
__device__ __forceinline__ float clip_log(float l) {
    float tx = 0.2f * l;
    tx = fminf(fmaxf(tx, -80.0f), 80.0f);
    float t = __expf(tx);
    return 10.0f * (t - 1.0f) * __builtin_amdgcn_rcpf(t + 1.0f);
}

// add_log_space branch combine; shared numeric pieces precomputed (sign-indep).
__device__ __forceinline__ void add_ls(float sx, float lx, float sy, float ly,
                                       float l_same_c, float nlog, bool zres, bool bx,
                                       float &s_o, float &l_o)
{
    bool zx = (sx == 0.0f);
    bool zy = (sy == 0.0f);
    bool both = (!zx) && (!zy);
    bool same_sign = (sx * sy > 0.0f);
    bool same_br = both && same_sign;
    bool opp_br  = both && !same_sign;

    float s = 0.0f, l = 0.0f;
    if ((!zx) && zy) { s = sx; l = lx; }
    if (zx && (!zy)) { s = sy; l = ly; }
    if (same_br) { s = (sx > 0.0f) ? 1.0f : -1.0f; l = l_same_c; }
    if (opp_br)  { s = zres ? 0.0f : (bx ? sx : sy); l = nlog; }
    s_o = s;
    l_o = clip_log(l);
}

// One fold step (verified numerics from round 3; absmax 0.0078).
__device__ __forceinline__ void step_fn(float ss, float sl,
    float p0, float p1, float p2, float p3, float p4,
    float inv_cs, float &as_, float &al, float &S)
{
    float d = sl - al;
    float mx = fmaxf(sl, al);
    float lse = mx + __logf(1.0f + __expf(-fabsf(d)));   // logaddexp
    float l_same_c = clip_log(lse);

    bool bx = (sl >= al);
    float big    = bx ? sl : al;
    float small_ = bx ? al : sl;
    float delta = fminf(fmaxf(small_ - big, -LOG_LIMF), -0.001f);
    float diff = __logf(1.0f - __expf(delta));           // log1p(-exp(delta))
    bool zres = (small_ == big);
    float nlog = zres ? 0.0f : (big + diff);

    float s_add, l_add, s_sub, l_sub;
    add_ls(ss, sl,  as_, al, l_same_c, nlog, zres, bx, s_add, l_add);
    add_ls(ss, sl, -as_, al, l_same_c, nlog, zres, bx, s_sub, l_sub);

    float sm   = ss * as_;
    float lmul = clip_log(sl + al);
    float ldiv = clip_log(sl - al);

    float rs = p0 * s_add + p1 * s_sub + (p2 + p3) * sm + p4 * ss;
    float rl = p0 * l_add + p1 * l_sub + p2 * lmul + p3 * ldiv + p4 * sl;

    float ms = fmaf(rl, rl, S) * inv_cs + 1e-6f;
    float scale = fminf(10.0f * __builtin_amdgcn_rsqf(ms), 1.0f);
    rl *= scale;

    S = fmaf(-sl, sl, S);   // retire sec's original log from suffix sum
    as_ = rs;
    al  = rl;
}

// Coalesced global gather of one ops chunk: flat f = lane + 64*i over the
// block's (64 elem x D dword) chunk; e=f/D (magic-div), d=f%D. Consecutive
// lanes read consecutive dwords except at elem boundaries (~2 jumps/inst).
template<int D, int OFF>
__device__ __forceinline__ void load_chunk(const float* __restrict__ opsB,
                                           unsigned lane, float* G)
{
#pragma unroll
    for (int i = 0; i < D; ++i) {
        unsigned f = lane + 64u * i;
        unsigned e = f / (unsigned)D;
        unsigned d = f - e * (unsigned)D;
        G[i] = opsB[e * ROW + OFF + d];
    }
}

// LDS write is lane-linear (f -> f): conflict-free, banks consecutive.
template<int D>
__device__ __forceinline__ void write_chunk(float* lds, unsigned lane, const float* G)
{
#pragma unroll
    for (int i = 0; i < D; ++i) lds[lane + 64u * i] = G[i];
}

// Compute STEPS fold steps reading probs from LDS at per-elem stride STRIDE.
// Read banks: (STRIDE*t + x) mod 32 with STRIDE in {35,15} coprime to 32 ->
// exactly 2-way aliasing = free.
template<int STEPS, int STRIDE, int KBASE>
__device__ __forceinline__ void compute_chunk(const float* lds, unsigned lane,
    const float* s_arr, const float* l_arr, float &as_, float &al, float &S)
{
    const float* my = lds + lane * STRIDE;
#pragma unroll
    for (int j = 0; j < STEPS; ++j) {
        const int k = KBASE + j;                         // compile-time
        float p0 = my[5*j + 0];
        float p1 = my[5*j + 1];
        float p2 = my[5*j + 2];
        float p3 = my[5*j + 3];
        float p4 = my[5*j + 4];
        step_fn(s_arr[30 - k], l_arr[30 - k], p0, p1, p2, p3, p4,
                1.0f / (float)(N_STACK - k), as_, al, S);
    }
}

// Grid = 2048 one-wave blocks on 1024 SIMDs -> 2 waves/SIMD max; tell the
// allocator so it can use up to ~256 VGPRs instead of sinking loads.
__global__ __launch_bounds__(BLOCK)
__attribute__((amdgpu_waves_per_eu(2, 2)))
void stack_fold_kernel(const float* __restrict__ sgn,
                       const float* __restrict__ logm,
                       const float* __restrict__ ops,
                       float* __restrict__ out, int n)
{
    __shared__ float lds[LDS_DW];          // 16.9 KB: stack staging, then ops buf

    const unsigned lane = threadIdx.x;     // 0..63, one wave
    const unsigned blk  = blockIdx.x;
    const unsigned id   = blk * BLOCK + lane;

    const float* opsB = ops + (size_t)blk * BLOCK * ROW;

    // ---- issue chunk0 ops loads first; latency hides under stack staging ----
    float G[CH_DW];
    load_chunk<CH_DW, 0>(opsB, lane, G);
    SB();

    // ---- stack staging: coalesced float4 loads (1 KB/inst) ----
    const float4* sg4 = reinterpret_cast<const float4*>(sgn  + (size_t)blk * BLOCK * N_STACK);
    const float4* lg4 = reinterpret_cast<const float4*>(logm + (size_t)blk * BLOCK * N_STACK);
    float4 sv[8], lv[8];
#pragma unroll
    for (int i = 0; i < 8; ++i) { sv[i] = sg4[lane + 64u*i]; lv[i] = lg4[lane + 64u*i]; }
    SB();

    // Transpose into LDS rows of SPAD=33 dwords (conflict-free within 2-way).
    // float4 #g4 (g4 = lane + 64*i) holds elem e=g4/8, dwords 4p..4p+3 (p=g4%8).
    {
        unsigned e0 = lane >> 3, pb = (lane & 7u) * 4u;
#pragma unroll
        for (int i = 0; i < 8; ++i) {
            unsigned base = (e0 + 8u*i) * SPAD + pb;
            lds[base+0] = sv[i].x; lds[base+1] = sv[i].y;
            lds[base+2] = sv[i].z; lds[base+3] = sv[i].w;
            lds[64*SPAD + base+0] = lv[i].x; lds[64*SPAD + base+1] = lv[i].y;
            lds[64*SPAD + base+2] = lv[i].z; lds[64*SPAD + base+3] = lv[i].w;
        }
    }
    // Single wave: LDS ops are in-order; no barrier needed anywhere.

    // ---- read own stack slice to registers ----
    float s_arr[N_STACK], l_arr[N_STACK];
#pragma unroll
    for (int j = 0; j < N_STACK; ++j) {
        s_arr[j] = lds[lane * SPAD + j];
        l_arr[j] = lds[64*SPAD + lane * SPAD + j];
    }

    // Suffix sum-of-squares of original logs 0..30; accumulator = top (31).
    float S = 0.0f;
#pragma unroll
    for (int i = 0; i < N_STACK - 1; ++i) S = fmaf(l_arr[i], l_arr[i], S);
    float as_ = s_arr[N_STACK - 1];
    float al  = l_arr[N_STACK - 1];

    // ---- software-pipelined chunk loop (LDS buf overlays stack region) ----
    write_chunk<CH_DW>(lds, lane, G);          // chunk0 -> LDS (loads long done)
    load_chunk<CH_DW, 1*CH_DW>(opsB, lane, G); // issue chunk1
    SB();
    compute_chunk<CH, CH_DW, 0>(lds, lane, s_arr, l_arr, as_, al, S);
    SB();

    write_chunk<CH_DW>(lds, lane, G);          // chunk1
    load_chunk<CH_DW, 2*CH_DW>(opsB, lane, G); // issue chunk2
    SB();
    compute_chunk<CH, CH_DW, CH>(lds, lane, s_arr, l_arr, as_, al, S);
    SB();

    write_chunk<CH_DW>(lds, lane, G);          // chunk2
    load_chunk<CH_DW, 3*CH_DW>(opsB, lane, G); // issue chunk3
    SB();
    compute_chunk<CH, CH_DW, 2*CH>(lds, lane, s_arr, l_arr, as_, al, S);
    SB();

    write_chunk<CH_DW>(lds, lane, G);          // chunk3
    load_chunk<LAST_DW, 4*CH_DW>(opsB, lane, G); // issue chunk4 (15 dw, in-bounds)
    SB();
    compute_chunk<CH, CH_DW, 3*CH>(lds, lane, s_arr, l_arr, as_, al, S);
    SB();

    write_chunk<LAST_DW>(lds, lane, G);        // chunk4 (stride 15 layout)
    SB();
    compute_chunk<LAST_ST, LAST_DW, 4*CH>(lds, lane, s_arr, l_arr, as_, al, S);

    // Output: (2, B, T) flat — [0..n) sign, [n..2n) log. Coalesced dword stores.
    out[id]     = as_;
    out[n + id] = al;
}

extern "C" void kernel_launch(void* const* d_in, const int* in_sizes, int n_in,
                              void* d_out, int out_size, void* d_ws, size_t ws_size,
                              hipStream_t stream) {
    const float* sgn  = (const float*)d_in[0];
    const float* logm = (const float*)d_in[1];
    const float* ops  = (const float*)d_in[2];
    float* out = (float*)d_out;

    int n = in_sizes[0] / N_STACK;        // B*T = 131072 (divisible by 64)
    int blocks = n / BLOCK;               // 2048 one-wave blocks
    stack_fold_kernel<<<blocks, BLOCK, 0, stream>>>(sgn, logm, ops, out, n);
}

// Round 5
// 152.277 us; speedup vs baseline: 1.0177x; 1.0177x over previous
//
#include <hip/hip_runtime.h>
#include <math.h>

// Problem constants: B=16, T=8192, N=32, depth=31, 5 ops. n = 131072 elements.
constexpr int N_STACK = 32;
constexpr int DEPTH   = 31;
constexpr int NOPS    = 5;
constexpr int BLOCK   = 256;
constexpr int WAVES   = BLOCK / 64;
constexpr int ROW     = DEPTH * NOPS;   // 155 dwords per elem
constexpr int SPAD    = 33;             // padded LDS row (bank-conflict-free)

#define LOG_LIMF 10.0f
#define PIN(x) asm volatile("" : "+v"(x))   // pin value in VGPR; blocks load re-sinking

// 16-B vector with 4-B alignment (ops rows are misaligned mod 16).
typedef float f4 __attribute__((ext_vector_type(4), aligned(4)));
__device__ __forceinline__ f4 ld4(const float* p) { return *reinterpret_cast<const f4*>(p); }

// _clip_log(l) = tanh(l/10)*10, via tanh(x) = (e^{2x}-1)/(e^{2x}+1)
__device__ __forceinline__ float clip_log(float l) {
    float tx = 0.2f * l;
    tx = fminf(fmaxf(tx, -80.0f), 80.0f);
    float t = __expf(tx);
    return 10.0f * (t - 1.0f) * __builtin_amdgcn_rcpf(t + 1.0f);
}

// add_log_space branch combine; shared numeric pieces precomputed (sign-indep).
__device__ __forceinline__ void add_ls(float sx, float lx, float sy, float ly,
                                       float l_same_c, float nlog, bool zres, bool bx,
                                       float &s_o, float &l_o)
{
    bool zx = (sx == 0.0f);
    bool zy = (sy == 0.0f);
    bool both = (!zx) && (!zy);
    bool same_sign = (sx * sy > 0.0f);
    bool same_br = both && same_sign;
    bool opp_br  = both && !same_sign;

    float s = 0.0f, l = 0.0f;
    if ((!zx) && zy) { s = sx; l = lx; }
    if (zx && (!zy)) { s = sy; l = ly; }
    if (same_br) { s = (sx > 0.0f) ? 1.0f : -1.0f; l = l_same_c; }
    if (opp_br)  { s = zres ? 0.0f : (bx ? sx : sy); l = nlog; }
    s_o = s;
    l_o = clip_log(l);
}

// One fold step (verified numerics; absmax 0.0078 across rounds 1-4).
__device__ __forceinline__ void step_fn(float ss, float sl,
    float p0, float p1, float p2, float p3, float p4,
    float inv_cs, float &as_, float &al, float &S)
{
    float d = sl - al;
    float mx = fmaxf(sl, al);
    float lse = mx + __logf(1.0f + __expf(-fabsf(d)));   // logaddexp
    float l_same_c = clip_log(lse);

    bool bx = (sl >= al);
    float big    = bx ? sl : al;
    float small_ = bx ? al : sl;
    float delta = fminf(fmaxf(small_ - big, -LOG_LIMF), -0.001f);
    float diff = __logf(1.0f - __expf(delta));           // log1p(-exp(delta))
    bool zres = (small_ == big);
    float nlog = zres ? 0.0f : (big + diff);

    float s_add, l_add, s_sub, l_sub;
    add_ls(ss, sl,  as_, al, l_same_c, nlog, zres, bx, s_add, l_add);
    add_ls(ss, sl, -as_, al, l_same_c, nlog, zres, bx, s_sub, l_sub);

    float sm   = ss * as_;
    float lmul = clip_log(sl + al);
    float ldiv = clip_log(sl - al);

    float rs = p0 * s_add + p1 * s_sub + (p2 + p3) * sm + p4 * ss;
    float rl = p0 * l_add + p1 * l_sub + p2 * lmul + p3 * ldiv + p4 * sl;

    float ms = fmaf(rl, rl, S) * inv_cs + 1e-6f;
    float scale = fminf(10.0f * __builtin_amdgcn_rsqf(ms), 1.0f);
    rl *= scale;

    S = fmaf(-sl, sl, S);   // retire sec's original log from suffix sum
    as_ = rs;
    al  = rl;
}

// STEPS fold steps, probs from f4 chunk buffer; all indices compile-time.
template<int KBASE, int JBASE, int STEPS>
__device__ __forceinline__ void stage(const f4* ch, const float* s_arr, const float* l_arr,
                                      float &as_, float &al, float &S)
{
#pragma unroll
    for (int j = 0; j < STEPS; ++j) {
        const int k = KBASE + j;
        const int q = 5 * (JBASE + j);
        float p0 = ch[(q+0)>>2][(q+0)&3];
        float p1 = ch[(q+1)>>2][(q+1)&3];
        float p2 = ch[(q+2)>>2][(q+2)&3];
        float p3 = ch[(q+3)>>2][(q+3)&3];
        float p4 = ch[(q+4)>>2][(q+4)&3];
        step_fn(s_arr[30-k], l_arr[30-k], p0, p1, p2, p3, p4,
                1.0f / (float)(N_STACK - k), as_, al, S);
    }
}

// 512 blocks x 4 waves = 2048 waves on 1024 SIMDs -> 2 waves/SIMD cap; tell RA.
__global__ __launch_bounds__(BLOCK)
__attribute__((amdgpu_waves_per_eu(2, 2)))
void stack_fold_kernel(const float* __restrict__ sgn,
                       const float* __restrict__ logm,
                       const float* __restrict__ ops,
                       float* __restrict__ out, int n)
{
    __shared__ float lds[WAVES * 64 * SPAD];   // 33.8 KB: per-wave stack transpose
    const unsigned lane = threadIdx.x & 63u;
    const unsigned wid  = threadIdx.x >> 6;
    const unsigned id   = blockIdx.x * BLOCK + threadIdx.x;
    float* myl = lds + wid * (64u * SPAD);     // this wave's private region: no barriers

    const float* row = ops + (size_t)id * ROW;
    const unsigned we0 = blockIdx.x * BLOCK + wid * 64u;   // wave's first element
    const f4* sg4 = reinterpret_cast<const f4*>(sgn  + (size_t)we0 * N_STACK);
    const f4* lg4 = reinterpret_cast<const f4*>(logm + (size_t)we0 * N_STACK);

    // ---- issue ALL early loads: stack (coalesced), then ops chunks 0 and 1.
    // In-order vmcnt: waiting on stack values keeps chunk 0/1 loads in flight.
    f4 sv[8], lv[8];
#pragma unroll
    for (int i = 0; i < 8; ++i) sv[i] = sg4[lane + 64u*i];
#pragma unroll
    for (int i = 0; i < 8; ++i) lv[i] = lg4[lane + 64u*i];
    f4 A[10], B[10], C[10];
#pragma unroll
    for (int i = 0; i < 10; ++i) A[i] = ld4(row + 4*i);         // chunk0: steps 0-7
#pragma unroll
    for (int i = 0; i < 10; ++i) B[i] = ld4(row + 40 + 4*i);    // chunk1: steps 8-15

    // ---- two-pass LDS transpose (region reused; same-wave LDS ops are ordered)
    const unsigned e0 = lane >> 3, pb = (lane & 7u) * 4u;
    float s_arr[N_STACK], l_arr[N_STACK];
#pragma unroll
    for (int i = 0; i < 8; ++i) {
        unsigned base = (e0 + 8u*i) * SPAD + pb;
        myl[base+0] = sv[i].x; myl[base+1] = sv[i].y;
        myl[base+2] = sv[i].z; myl[base+3] = sv[i].w;
    }
#pragma unroll
    for (int j = 0; j < N_STACK; ++j) s_arr[j] = myl[lane*SPAD + j];
#pragma unroll
    for (int i = 0; i < 8; ++i) {
        unsigned base = (e0 + 8u*i) * SPAD + pb;
        myl[base+0] = lv[i].x; myl[base+1] = lv[i].y;
        myl[base+2] = lv[i].z; myl[base+3] = lv[i].w;
    }
#pragma unroll
    for (int j = 0; j < N_STACK; ++j) l_arr[j] = myl[lane*SPAD + j];
#pragma unroll
    for (int j = 0; j < N_STACK; ++j) { PIN(s_arr[j]); PIN(l_arr[j]); }

    // Suffix sum-of-squares of original logs 0..30; accumulator = top (31).
    float S = 0.0f;
#pragma unroll
    for (int i = 0; i < N_STACK - 1; ++i) S = fmaf(l_arr[i], l_arr[i], S);
    float as_ = s_arr[N_STACK - 1];
    float al  = l_arr[N_STACK - 1];

    // ---- stage 0: steps 0..7 from A; chunk2 (C) issued mid-stage, consumed
    //      two compute-stages later -> ~9k cycles of latency cover.
#pragma unroll
    for (int i = 0; i < 10; ++i) PIN(A[i]);
    stage<0, 0, 3>(A, s_arr, l_arr, as_, al, S);
#pragma unroll
    for (int i = 0; i < 10; ++i) C[i] = ld4(row + 80 + 4*i);    // chunk2: steps 16-23
    stage<3, 3, 5>(A, s_arr, l_arr, as_, al, S);

    // ---- stage 1: steps 8..15 from B; issue chunk3 (last, 35 dw) into A.
#pragma unroll
    for (int i = 0; i < 10; ++i) PIN(B[i]);
    stage<8, 0, 3>(B, s_arr, l_arr, as_, al, S);
#pragma unroll
    for (int i = 0; i < 8; ++i) A[i] = ld4(row + 120 + 4*i);    // dwords 120..151
    {   // last 3 dwords (152..154) — no overread past the ops buffer
        float t0 = row[152], t1 = row[153], t2 = row[154];
        f4 t; t.x = t0; t.y = t1; t.z = t2; t.w = 0.0f;
        A[8] = t;
    }
    stage<11, 3, 5>(B, s_arr, l_arr, as_, al, S);

    // ---- stage 2: steps 16..23 from C (loads landed ~2 stages ago).
#pragma unroll
    for (int i = 0; i < 10; ++i) PIN(C[i]);
    stage<16, 0, 8>(C, s_arr, l_arr, as_, al, S);

    // ---- stage 3: steps 24..30 from refilled A.
#pragma unroll
    for (int i = 0; i < 9; ++i) PIN(A[i]);
    stage<24, 0, 7>(A, s_arr, l_arr, as_, al, S);

    // Output: (2, B, T) flat — [0..n) sign, [n..2n) log. Coalesced stores.
    out[id]     = as_;
    out[n + id] = al;
}

extern "C" void kernel_launch(void* const* d_in, const int* in_sizes, int n_in,
                              void* d_out, int out_size, void* d_ws, size_t ws_size,
                              hipStream_t stream) {
    const float* sgn  = (const float*)d_in[0];
    const float* logm = (const float*)d_in[1];
    const float* ops  = (const float*)d_in[2];
    float* out = (float*)d_out;

    int n = in_sizes[0] / N_STACK;        // B*T = 131072
    int blocks = n / BLOCK;               // 512 blocks x 256 threads
    stack_fold_kernel<<<blocks, BLOCK, 0, stream>>>(sgn, logm, ops, out, n);
}